// Round 1
// baseline (514.900 us; speedup 1.0000x reference)
//
#include <hip/hip_runtime.h>
#include <math.h>

#define N_NODES   1000000
#define N_EDGES   16000000
#define NUM_GRAPHS 64
#define LATENT    128

// ws layout (doubles):
// [0] recon_sum  [1] S1 (sum len)  [2] S2 (sum len^2)  [3] kl_sum
// [4..68)  graph sum x
// [68..132) graph sum y
// [132..196) graph counts
#define WS_DOUBLES 200

__device__ __forceinline__ double block_reduce_d(double v, double* smem) {
    // wave-64 butterfly then cross-wave via LDS
    for (int off = 32; off > 0; off >>= 1) v += __shfl_down(v, off);
    const int lane = threadIdx.x & 63;
    const int wid  = threadIdx.x >> 6;
    if (lane == 0) smem[wid] = v;
    __syncthreads();
    double tot = 0.0;
    if (threadIdx.x == 0) {
        const int nw = blockDim.x >> 6;
        for (int w = 0; w < nw; ++w) tot += smem[w];
    }
    return tot; // valid on thread 0 only
}

__global__ void init_ws(double* ws) {
    int t = blockIdx.x * blockDim.x + threadIdx.x;
    if (t < WS_DOUBLES) ws[t] = 0.0;
}

__global__ void node_pass(const float2* __restrict__ pred,
                          const float2* __restrict__ targ,
                          const int*    __restrict__ batch,
                          double* __restrict__ ws) {
    __shared__ float sgx[NUM_GRAPHS];
    __shared__ float sgy[NUM_GRAPHS];
    __shared__ int   scnt[NUM_GRAPHS];
    __shared__ double smem[8];

    for (int g = threadIdx.x; g < NUM_GRAPHS; g += blockDim.x) {
        sgx[g] = 0.f; sgy[g] = 0.f; scnt[g] = 0;
    }
    __syncthreads();

    float recon = 0.f;
    const int idx = blockIdx.x * blockDim.x + threadIdx.x;
    const int stride = gridDim.x * blockDim.x;
    for (int n = idx; n < N_NODES; n += stride) {
        float2 p = pred[n];
        float2 t = targ[n];
        float dx = p.x - t.x, dy = p.y - t.y;
        recon += dx * dx + dy * dy;
        int b = batch[n];
        atomicAdd(&sgx[b], p.x);
        atomicAdd(&sgy[b], p.y);
        atomicAdd(&scnt[b], 1);
    }

    double r = block_reduce_d((double)recon, smem);
    if (threadIdx.x == 0) atomicAdd(&ws[0], r);
    __syncthreads();

    for (int g = threadIdx.x; g < NUM_GRAPHS; g += blockDim.x) {
        if (scnt[g] != 0) {
            atomicAdd(&ws[4 + g],   (double)sgx[g]);
            atomicAdd(&ws[68 + g],  (double)sgy[g]);
            atomicAdd(&ws[132 + g], (double)scnt[g]);
        }
    }
}

__global__ void edge_pass(const float2* __restrict__ pred,
                          const int*    __restrict__ ei,   // [2 * N_EDGES]
                          double* __restrict__ ws) {
    __shared__ double smem1[8];
    __shared__ double smem2[8];

    float s1 = 0.f;  // sum of edge lengths (per-thread partial, ~30-60 values)
    float s2 = 0.f;  // sum of squared edge lengths
    const int idx = blockIdx.x * blockDim.x + threadIdx.x;
    const int stride = gridDim.x * blockDim.x;
    for (int e = idx; e < N_EDGES; e += stride) {
        int i = ei[e];
        int j = ei[N_EDGES + e];
        float2 pi = pred[i];
        float2 pj = pred[j];
        float dx = pi.x - pj.x, dy = pi.y - pj.y;
        float l2 = dx * dx + dy * dy;
        s2 += l2;
        s1 += sqrtf(l2);
    }

    // two reductions; reuse pattern with separate smem to avoid extra syncs
    double r1 = (double)s1, r2 = (double)s2;
    for (int off = 32; off > 0; off >>= 1) {
        r1 += __shfl_down(r1, off);
        r2 += __shfl_down(r2, off);
    }
    const int lane = threadIdx.x & 63;
    const int wid  = threadIdx.x >> 6;
    if (lane == 0) { smem1[wid] = r1; smem2[wid] = r2; }
    __syncthreads();
    if (threadIdx.x == 0) {
        double t1 = 0.0, t2 = 0.0;
        const int nw = blockDim.x >> 6;
        for (int w = 0; w < nw; ++w) { t1 += smem1[w]; t2 += smem2[w]; }
        atomicAdd(&ws[1], t1);
        atomicAdd(&ws[2], t2);
    }
}

__global__ void kl_pass(const float* __restrict__ mu,
                        const float* __restrict__ logvar,
                        double* __restrict__ ws) {
    __shared__ double smem[8];
    double s = 0.0;
    for (int t = threadIdx.x; t < NUM_GRAPHS * LATENT; t += blockDim.x) {
        float m = mu[t], lv = logvar[t];
        s += (double)(1.0f + lv - m * m - expf(lv));
    }
    double r = block_reduce_d(s, smem);
    if (threadIdx.x == 0) atomicAdd(&ws[3], r);
}

__global__ void finalize(const double* __restrict__ ws,
                         const int* __restrict__ epoch_p,
                         float* __restrict__ out) {
    double recon = ws[0] / (2.0 * (double)N_NODES);
    double S1 = ws[1], S2 = ws[2];
    double lap  = S2 / (double)N_EDGES;
    double arap = (S2 - S1 * S1 / (double)N_EDGES) / ((double)N_EDGES - 1.0);
    double drift = 0.0;
    for (int g = 0; g < NUM_GRAPHS; ++g) {
        double c  = ws[132 + g];
        double mx = ws[4 + g] / c;
        double my = ws[68 + g] / c;
        drift += mx * mx + my * my;
    }
    drift /= (double)NUM_GRAPHS;
    double kl = -0.5 * ws[3] / (double)NUM_GRAPHS;
    int epoch = *epoch_p;
    double beta = (epoch < 10) ? ((double)epoch / 10.0) : 1.0;
    out[0] = (float)(recon + 0.1 * lap + 0.01 * drift + 0.1 * arap + beta * kl);
}

extern "C" void kernel_launch(void* const* d_in, const int* in_sizes, int n_in,
                              void* d_out, int out_size, void* d_ws, size_t ws_size,
                              hipStream_t stream) {
    const float2* pred   = (const float2*)d_in[0];
    const float2* targ   = (const float2*)d_in[1];
    const int*    ei     = (const int*)d_in[2];
    const int*    batch  = (const int*)d_in[3];
    const float*  mu     = (const float*)d_in[4];
    const float*  logvar = (const float*)d_in[5];
    const int*    epoch  = (const int*)d_in[6];
    float* out = (float*)d_out;
    double* ws = (double*)d_ws;

    init_ws<<<1, 256, 0, stream>>>(ws);
    node_pass<<<1024, 256, 0, stream>>>(pred, targ, batch, ws);
    edge_pass<<<2048, 256, 0, stream>>>(pred, ei, ws);
    kl_pass<<<1, 256, 0, stream>>>(mu, logvar, ws);
    finalize<<<1, 1, 0, stream>>>(ws, epoch, out);
}

// Round 3
// 376.301 us; speedup vs baseline: 1.3683x; 1.3683x over previous
//
#include <hip/hip_runtime.h>
#include <hip/hip_fp16.h>
#include <math.h>

#define N_NODES    1000000
#define N_EDGES    16000000
#define NUM_GRAPHS 64
#define LATENT     128

// ws layout:
// doubles [0..200): [0] recon_sum [1] S1 [2] S2 [3] kl_sum
//   [4..68) graph sum x, [68..132) graph sum y, [132..196) graph counts
// bytes [2048 .. 2048 + 4*N_NODES): packed half2 pred table
#define WS_DOUBLES 200
#define PACKED_OFFSET 2048

typedef int vint4 __attribute__((ext_vector_type(4)));  // native vector for nontemporal builtin

__global__ void init_ws(double* ws) {
    int t = blockIdx.x * blockDim.x + threadIdx.x;
    if (t < WS_DOUBLES) ws[t] = 0.0;
}

__global__ void node_pass(const float2* __restrict__ pred,
                          const float2* __restrict__ targ,
                          const int*    __restrict__ batch,
                          double* __restrict__ ws,
                          unsigned* __restrict__ packed) {  // may be null
    __shared__ float sgx[NUM_GRAPHS];
    __shared__ float sgy[NUM_GRAPHS];
    __shared__ int   scnt[NUM_GRAPHS];
    __shared__ double smem[8];

    for (int g = threadIdx.x; g < NUM_GRAPHS; g += blockDim.x) {
        sgx[g] = 0.f; sgy[g] = 0.f; scnt[g] = 0;
    }
    __syncthreads();

    float recon = 0.f;
    const int idx = blockIdx.x * blockDim.x + threadIdx.x;
    const int stride = gridDim.x * blockDim.x;
    for (int n = idx; n < N_NODES; n += stride) {
        float2 p = pred[n];
        float2 t = targ[n];
        float dx = p.x - t.x, dy = p.y - t.y;
        recon += dx * dx + dy * dy;

        if (packed) {
            __half2 h = __floats2half2_rn(p.x, p.y);
            packed[n] = *reinterpret_cast<unsigned*>(&h);
        }

        int b = batch[n];
        // batch is sorted: waves are almost always graph-uniform.
        unsigned long long act = __ballot(1);
        int b0 = __shfl(b, 0);
        bool fast = (act == ~0ull) && (__ballot(b == b0) == act);
        if (fast) {
            float sx = p.x, sy = p.y;
            #pragma unroll
            for (int off = 32; off > 0; off >>= 1) {
                sx += __shfl_xor(sx, off);
                sy += __shfl_xor(sy, off);
            }
            if ((threadIdx.x & 63) == 0) {
                atomicAdd(&sgx[b0], sx);
                atomicAdd(&sgy[b0], sy);
                atomicAdd(&scnt[b0], 64);
            }
        } else {
            atomicAdd(&sgx[b], p.x);
            atomicAdd(&sgy[b], p.y);
            atomicAdd(&scnt[b], 1);
        }
    }

    // reduce recon across block
    double r = (double)recon;
    #pragma unroll
    for (int off = 32; off > 0; off >>= 1) r += __shfl_down(r, off);
    const int lane = threadIdx.x & 63;
    const int wid  = threadIdx.x >> 6;
    if (lane == 0) smem[wid] = r;
    __syncthreads();
    if (threadIdx.x == 0) {
        double tot = 0.0;
        const int nw = blockDim.x >> 6;
        for (int w = 0; w < nw; ++w) tot += smem[w];
        atomicAdd(&ws[0], tot);
    }

    for (int g = threadIdx.x; g < NUM_GRAPHS; g += blockDim.x) {
        if (scnt[g] != 0) {
            atomicAdd(&ws[4 + g],   (double)sgx[g]);
            atomicAdd(&ws[68 + g],  (double)sgy[g]);
            atomicAdd(&ws[132 + g], (double)scnt[g]);
        }
    }
}

__device__ __forceinline__ void edge_flush(float s1, float s2, double* ws,
                                           double* smem1, double* smem2) {
    double r1 = (double)s1, r2 = (double)s2;
    #pragma unroll
    for (int off = 32; off > 0; off >>= 1) {
        r1 += __shfl_down(r1, off);
        r2 += __shfl_down(r2, off);
    }
    const int lane = threadIdx.x & 63;
    const int wid  = threadIdx.x >> 6;
    if (lane == 0) { smem1[wid] = r1; smem2[wid] = r2; }
    __syncthreads();
    if (threadIdx.x == 0) {
        double t1 = 0.0, t2 = 0.0;
        const int nw = blockDim.x >> 6;
        for (int w = 0; w < nw; ++w) { t1 += smem1[w]; t2 += smem2[w]; }
        atomicAdd(&ws[1], t1);
        atomicAdd(&ws[2], t2);
    }
}

// Fast path: gather from 4 MB half2 table; nontemporal int4 index loads;
// 4 edges per thread-iteration for memory-level parallelism.
__global__ void edge_pass_packed(const unsigned* __restrict__ packed,
                                 const int* __restrict__ ei,
                                 double* __restrict__ ws) {
    __shared__ double smem1[8];
    __shared__ double smem2[8];

    float s1 = 0.f, s2 = 0.f;
    const int gid = blockIdx.x * blockDim.x + threadIdx.x;
    const int stride = gridDim.x * blockDim.x;
    const int ngroups = N_EDGES / 4;
    const vint4* eia = (const vint4*)ei;
    const vint4* eib = (const vint4*)(ei + N_EDGES);

    for (int g = gid; g < ngroups; g += stride) {
        vint4 a = __builtin_nontemporal_load(eia + g);
        vint4 b = __builtin_nontemporal_load(eib + g);
        // issue all 8 gathers before consuming
        unsigned pa0 = packed[a.x], pb0 = packed[b.x];
        unsigned pa1 = packed[a.y], pb1 = packed[b.y];
        unsigned pa2 = packed[a.z], pb2 = packed[b.z];
        unsigned pa3 = packed[a.w], pb3 = packed[b.w];

        #pragma unroll
        for (int k = 0; k < 4; ++k) {
            unsigned ua = (k == 0) ? pa0 : (k == 1) ? pa1 : (k == 2) ? pa2 : pa3;
            unsigned ub = (k == 0) ? pb0 : (k == 1) ? pb1 : (k == 2) ? pb2 : pb3;
            __half2 ha = *reinterpret_cast<__half2*>(&ua);
            __half2 hb = *reinterpret_cast<__half2*>(&ub);
            float2 fa = __half22float2(ha);
            float2 fb = __half22float2(hb);
            float dx = fa.x - fb.x, dy = fa.y - fb.y;
            float l2 = dx * dx + dy * dy;
            s2 += l2;
            s1 += sqrtf(l2);
        }
    }
    edge_flush(s1, s2, ws, smem1, smem2);
}

// Fallback (ws too small for packed table): original float2 gathers.
__global__ void edge_pass_f32(const float2* __restrict__ pred,
                              const int* __restrict__ ei,
                              double* __restrict__ ws) {
    __shared__ double smem1[8];
    __shared__ double smem2[8];

    float s1 = 0.f, s2 = 0.f;
    const int idx = blockIdx.x * blockDim.x + threadIdx.x;
    const int stride = gridDim.x * blockDim.x;
    for (int e = idx; e < N_EDGES; e += stride) {
        int i = ei[e];
        int j = ei[N_EDGES + e];
        float2 pi = pred[i];
        float2 pj = pred[j];
        float dx = pi.x - pj.x, dy = pi.y - pj.y;
        float l2 = dx * dx + dy * dy;
        s2 += l2;
        s1 += sqrtf(l2);
    }
    edge_flush(s1, s2, ws, smem1, smem2);
}

__global__ void kl_pass(const float* __restrict__ mu,
                        const float* __restrict__ logvar,
                        double* __restrict__ ws) {
    __shared__ double smem[8];
    double s = 0.0;
    for (int t = threadIdx.x; t < NUM_GRAPHS * LATENT; t += blockDim.x) {
        float m = mu[t], lv = logvar[t];
        s += (double)(1.0f + lv - m * m - expf(lv));
    }
    #pragma unroll
    for (int off = 32; off > 0; off >>= 1) s += __shfl_down(s, off);
    const int lane = threadIdx.x & 63;
    const int wid  = threadIdx.x >> 6;
    if (lane == 0) smem[wid] = s;
    __syncthreads();
    if (threadIdx.x == 0) {
        double tot = 0.0;
        const int nw = blockDim.x >> 6;
        for (int w = 0; w < nw; ++w) tot += smem[w];
        atomicAdd(&ws[3], tot);
    }
}

__global__ void finalize(const double* __restrict__ ws,
                         const int* __restrict__ epoch_p,
                         float* __restrict__ out) {
    double recon = ws[0] / (2.0 * (double)N_NODES);
    double S1 = ws[1], S2 = ws[2];
    double lap  = S2 / (double)N_EDGES;
    double arap = (S2 - S1 * S1 / (double)N_EDGES) / ((double)N_EDGES - 1.0);
    double drift = 0.0;
    for (int g = 0; g < NUM_GRAPHS; ++g) {
        double c  = ws[132 + g];
        double mx = ws[4 + g] / c;
        double my = ws[68 + g] / c;
        drift += mx * mx + my * my;
    }
    drift /= (double)NUM_GRAPHS;
    double kl = -0.5 * ws[3] / (double)NUM_GRAPHS;
    int epoch = *epoch_p;
    double beta = (epoch < 10) ? ((double)epoch / 10.0) : 1.0;
    out[0] = (float)(recon + 0.1 * lap + 0.01 * drift + 0.1 * arap + beta * kl);
}

extern "C" void kernel_launch(void* const* d_in, const int* in_sizes, int n_in,
                              void* d_out, int out_size, void* d_ws, size_t ws_size,
                              hipStream_t stream) {
    const float2* pred   = (const float2*)d_in[0];
    const float2* targ   = (const float2*)d_in[1];
    const int*    ei     = (const int*)d_in[2];
    const int*    batch  = (const int*)d_in[3];
    const float*  mu     = (const float*)d_in[4];
    const float*  logvar = (const float*)d_in[5];
    const int*    epoch  = (const int*)d_in[6];
    float* out = (float*)d_out;
    double* ws = (double*)d_ws;

    const bool use_packed = ws_size >= (size_t)PACKED_OFFSET + 4ull * N_NODES;
    unsigned* packed = use_packed
        ? (unsigned*)((char*)d_ws + PACKED_OFFSET) : (unsigned*)nullptr;

    init_ws<<<1, 256, 0, stream>>>(ws);
    node_pass<<<1024, 256, 0, stream>>>(pred, targ, batch, ws, packed);
    if (use_packed)
        edge_pass_packed<<<2048, 256, 0, stream>>>(packed, ei, ws);
    else
        edge_pass_f32<<<2048, 256, 0, stream>>>(pred, ei, ws);
    kl_pass<<<1, 256, 0, stream>>>(mu, logvar, ws);
    finalize<<<1, 1, 0, stream>>>(ws, epoch, out);
}

// Round 4
// 364.759 us; speedup vs baseline: 1.4116x; 1.0316x over previous
//
#include <hip/hip_runtime.h>
#include <hip/hip_fp16.h>
#include <math.h>

#define N_NODES    1000000
#define N_EDGES    16000000
#define NUM_GRAPHS 64
#define LATENT     128

// ws layout:
// doubles [0..200): [0] recon_sum [1] S1 [2] S2 [3] kl_sum
//   [4..68) graph sum x, [68..132) graph sum y, [132..196) graph counts
// bytes [2048 .. 2048 + 4*N_NODES): packed half2 pred table
#define WS_DOUBLES 200
#define PACKED_OFFSET 2048

typedef int vint4 __attribute__((ext_vector_type(4)));

__global__ void init_ws(double* ws) {
    int t = blockIdx.x * blockDim.x + threadIdx.x;
    if (t < WS_DOUBLES) ws[t] = 0.0;
}

__global__ void node_kl_pass(const float2* __restrict__ pred,
                             const float2* __restrict__ targ,
                             const int*    __restrict__ batch,
                             const float*  __restrict__ mu,
                             const float*  __restrict__ logvar,
                             double* __restrict__ ws,
                             unsigned* __restrict__ packed) {  // may be null
    __shared__ float sgx[NUM_GRAPHS];
    __shared__ float sgy[NUM_GRAPHS];
    __shared__ int   scnt[NUM_GRAPHS];
    __shared__ double smem[8];

    for (int g = threadIdx.x; g < NUM_GRAPHS; g += blockDim.x) {
        sgx[g] = 0.f; sgy[g] = 0.f; scnt[g] = 0;
    }
    __syncthreads();

    float recon = 0.f;
    const int idx = blockIdx.x * blockDim.x + threadIdx.x;
    const int stride = gridDim.x * blockDim.x;
    for (int n = idx; n < N_NODES; n += stride) {
        float2 p = pred[n];
        float2 t = targ[n];
        float dx = p.x - t.x, dy = p.y - t.y;
        recon += dx * dx + dy * dy;

        if (packed) {
            __half2 h = __floats2half2_rn(p.x, p.y);
            packed[n] = *reinterpret_cast<unsigned*>(&h);
        }

        int b = batch[n];
        // batch is sorted: waves are almost always graph-uniform.
        unsigned long long act = __ballot(1);
        int b0 = __shfl(b, 0);
        bool fast = (act == ~0ull) && (__ballot(b == b0) == act);
        if (fast) {
            float sx = p.x, sy = p.y;
            #pragma unroll
            for (int off = 32; off > 0; off >>= 1) {
                sx += __shfl_xor(sx, off);
                sy += __shfl_xor(sy, off);
            }
            if ((threadIdx.x & 63) == 0) {
                atomicAdd(&sgx[b0], sx);
                atomicAdd(&sgy[b0], sy);
                atomicAdd(&scnt[b0], 64);
            }
        } else {
            atomicAdd(&sgx[b], p.x);
            atomicAdd(&sgy[b], p.y);
            atomicAdd(&scnt[b], 1);
        }
    }

    // reduce recon across block
    double r = (double)recon;
    #pragma unroll
    for (int off = 32; off > 0; off >>= 1) r += __shfl_down(r, off);
    const int lane = threadIdx.x & 63;
    const int wid  = threadIdx.x >> 6;
    if (lane == 0) smem[wid] = r;
    __syncthreads();
    if (threadIdx.x == 0) {
        double tot = 0.0;
        const int nw = blockDim.x >> 6;
        for (int w = 0; w < nw; ++w) tot += smem[w];
        atomicAdd(&ws[0], tot);
    }

    for (int g = threadIdx.x; g < NUM_GRAPHS; g += blockDim.x) {
        if (scnt[g] != 0) {
            atomicAdd(&ws[4 + g],   (double)sgx[g]);
            atomicAdd(&ws[68 + g],  (double)sgy[g]);
            atomicAdd(&ws[132 + g], (double)scnt[g]);
        }
    }

    // KL tail: block 0 only (8192 elements, trivial)
    if (blockIdx.x == 0) {
        double s = 0.0;
        for (int t = threadIdx.x; t < NUM_GRAPHS * LATENT; t += blockDim.x) {
            float m = mu[t], lv = logvar[t];
            s += (double)(1.0f + lv - m * m - expf(lv));
        }
        #pragma unroll
        for (int off = 32; off > 0; off >>= 1) s += __shfl_down(s, off);
        __syncthreads();
        if (lane == 0) smem[wid] = s;
        __syncthreads();
        if (threadIdx.x == 0) {
            double tot = 0.0;
            const int nw = blockDim.x >> 6;
            for (int w = 0; w < nw; ++w) tot += smem[w];
            atomicAdd(&ws[3], tot);
        }
    }
}

__device__ __forceinline__ void edge_flush(float s1, float s2, double* ws,
                                           double* smem1, double* smem2) {
    double r1 = (double)s1, r2 = (double)s2;
    #pragma unroll
    for (int off = 32; off > 0; off >>= 1) {
        r1 += __shfl_down(r1, off);
        r2 += __shfl_down(r2, off);
    }
    const int lane = threadIdx.x & 63;
    const int wid  = threadIdx.x >> 6;
    if (lane == 0) { smem1[wid] = r1; smem2[wid] = r2; }
    __syncthreads();
    if (threadIdx.x == 0) {
        double t1 = 0.0, t2 = 0.0;
        const int nw = blockDim.x >> 6;
        for (int w = 0; w < nw; ++w) { t1 += smem1[w]; t2 += smem2[w]; }
        atomicAdd(&ws[1], t1);
        atomicAdd(&ws[2], t2);
    }
}

// Gather from 4 MB half2 table; nontemporal index loads; 8 gathers in flight
// + next iteration's index vectors prefetched (issued AFTER the gathers so
// consuming the gathers only needs vmcnt(2) and the prefetch stays in flight).
__global__ void edge_pass_packed(const unsigned* __restrict__ packed,
                                 const int* __restrict__ ei,
                                 double* __restrict__ ws) {
    __shared__ double smem1[8];
    __shared__ double smem2[8];

    float s1 = 0.f, s2 = 0.f;
    const int gid = blockIdx.x * blockDim.x + threadIdx.x;
    const int stride = gridDim.x * blockDim.x;
    const int ngroups = N_EDGES / 4;
    const vint4* eia = (const vint4*)ei;
    const vint4* eib = (const vint4*)(ei + N_EDGES);

    int g = gid;
    if (g < ngroups) {
        vint4 a = __builtin_nontemporal_load(eia + g);
        vint4 b = __builtin_nontemporal_load(eib + g);
        while (true) {
            // 1) issue the 8 gathers for the current group
            unsigned pa0 = packed[a.x], pb0 = packed[b.x];
            unsigned pa1 = packed[a.y], pb1 = packed[b.y];
            unsigned pa2 = packed[a.z], pb2 = packed[b.z];
            unsigned pa3 = packed[a.w], pb3 = packed[b.w];

            // 2) issue next iteration's index loads (prefetch)
            const int gn = g + stride;
            const bool more = gn < ngroups;
            vint4 an = {0, 0, 0, 0}, bn = {0, 0, 0, 0};
            if (more) {
                an = __builtin_nontemporal_load(eia + gn);
                bn = __builtin_nontemporal_load(eib + gn);
            }

            // 3) consume gathers (vmcnt(2): prefetch still outstanding)
            {
                __half2 ha = *reinterpret_cast<__half2*>(&pa0);
                __half2 hb = *reinterpret_cast<__half2*>(&pb0);
                float2 fa = __half22float2(ha);
                float2 fb = __half22float2(hb);
                float dx = fa.x - fb.x, dy = fa.y - fb.y;
                float l2 = dx * dx + dy * dy;
                s2 += l2; s1 += sqrtf(l2);
            }
            {
                __half2 ha = *reinterpret_cast<__half2*>(&pa1);
                __half2 hb = *reinterpret_cast<__half2*>(&pb1);
                float2 fa = __half22float2(ha);
                float2 fb = __half22float2(hb);
                float dx = fa.x - fb.x, dy = fa.y - fb.y;
                float l2 = dx * dx + dy * dy;
                s2 += l2; s1 += sqrtf(l2);
            }
            {
                __half2 ha = *reinterpret_cast<__half2*>(&pa2);
                __half2 hb = *reinterpret_cast<__half2*>(&pb2);
                float2 fa = __half22float2(ha);
                float2 fb = __half22float2(hb);
                float dx = fa.x - fb.x, dy = fa.y - fb.y;
                float l2 = dx * dx + dy * dy;
                s2 += l2; s1 += sqrtf(l2);
            }
            {
                __half2 ha = *reinterpret_cast<__half2*>(&pa3);
                __half2 hb = *reinterpret_cast<__half2*>(&pb3);
                float2 fa = __half22float2(ha);
                float2 fb = __half22float2(hb);
                float dx = fa.x - fb.x, dy = fa.y - fb.y;
                float l2 = dx * dx + dy * dy;
                s2 += l2; s1 += sqrtf(l2);
            }

            if (!more) break;
            g = gn; a = an; b = bn;
        }
    }
    edge_flush(s1, s2, ws, smem1, smem2);
}

// Fallback (ws too small for packed table): original float2 gathers.
__global__ void edge_pass_f32(const float2* __restrict__ pred,
                              const int* __restrict__ ei,
                              double* __restrict__ ws) {
    __shared__ double smem1[8];
    __shared__ double smem2[8];

    float s1 = 0.f, s2 = 0.f;
    const int idx = blockIdx.x * blockDim.x + threadIdx.x;
    const int stride = gridDim.x * blockDim.x;
    for (int e = idx; e < N_EDGES; e += stride) {
        int i = ei[e];
        int j = ei[N_EDGES + e];
        float2 pi = pred[i];
        float2 pj = pred[j];
        float dx = pi.x - pj.x, dy = pi.y - pj.y;
        float l2 = dx * dx + dy * dy;
        s2 += l2;
        s1 += sqrtf(l2);
    }
    edge_flush(s1, s2, ws, smem1, smem2);
}

__global__ void finalize(const double* __restrict__ ws,
                         const int* __restrict__ epoch_p,
                         float* __restrict__ out) {
    double recon = ws[0] / (2.0 * (double)N_NODES);
    double S1 = ws[1], S2 = ws[2];
    double lap  = S2 / (double)N_EDGES;
    double arap = (S2 - S1 * S1 / (double)N_EDGES) / ((double)N_EDGES - 1.0);
    double drift = 0.0;
    for (int g = 0; g < NUM_GRAPHS; ++g) {
        double c  = ws[132 + g];
        double mx = ws[4 + g] / c;
        double my = ws[68 + g] / c;
        drift += mx * mx + my * my;
    }
    drift /= (double)NUM_GRAPHS;
    double kl = -0.5 * ws[3] / (double)NUM_GRAPHS;
    int epoch = *epoch_p;
    double beta = (epoch < 10) ? ((double)epoch / 10.0) : 1.0;
    out[0] = (float)(recon + 0.1 * lap + 0.01 * drift + 0.1 * arap + beta * kl);
}

extern "C" void kernel_launch(void* const* d_in, const int* in_sizes, int n_in,
                              void* d_out, int out_size, void* d_ws, size_t ws_size,
                              hipStream_t stream) {
    const float2* pred   = (const float2*)d_in[0];
    const float2* targ   = (const float2*)d_in[1];
    const int*    ei     = (const int*)d_in[2];
    const int*    batch  = (const int*)d_in[3];
    const float*  mu     = (const float*)d_in[4];
    const float*  logvar = (const float*)d_in[5];
    const int*    epoch  = (const int*)d_in[6];
    float* out = (float*)d_out;
    double* ws = (double*)d_ws;

    const bool use_packed = ws_size >= (size_t)PACKED_OFFSET + 4ull * N_NODES;
    unsigned* packed = use_packed
        ? (unsigned*)((char*)d_ws + PACKED_OFFSET) : (unsigned*)nullptr;

    init_ws<<<1, 256, 0, stream>>>(ws);
    node_kl_pass<<<1024, 256, 0, stream>>>(pred, targ, batch, mu, logvar, ws, packed);
    if (use_packed)
        edge_pass_packed<<<2048, 256, 0, stream>>>(packed, ei, ws);
    else
        edge_pass_f32<<<2048, 256, 0, stream>>>(pred, ei, ws);
    finalize<<<1, 1, 0, stream>>>(ws, epoch, out);
}